// Round 23
// baseline (46.564 us; speedup 1.0000x reference)
//
#include <hip/hip_runtime.h>

#define BATCH 64
#define TLEN  2048
#define DDIM  256
#define ADIM  128
#define TM    64          // t-rows per tile
#define TILES 4           // tiles per block
#define NBLK  (BATCH * TLEN / (TILES * TM))   // 512 blocks, 8 per batch: single co-resident round
#define EPSC  1e-7f

typedef __bf16 bf16x8 __attribute__((ext_vector_type(8)));
typedef __bf16 bf16x4 __attribute__((ext_vector_type(4)));
typedef float  f32x4  __attribute__((ext_vector_type(4)));

// DPP-based add of a lane-permuted copy (VALU pipe, not LDS)
template <int CTRL>
__device__ __forceinline__ float dpp_add(float v) {
    int vi = __builtin_bit_cast(int, v);
    int sw = __builtin_amdgcn_update_dpp(vi, vi, CTRL, 0xF, 0xF, false);
    return v + __builtin_bit_cast(float, sw);
}

// raw workgroup barrier: orders LDS only, leaves global loads (vmcnt) in flight
__device__ __forceinline__ void bar_lds() {
    asm volatile("s_waitcnt lgkmcnt(0)" ::: "memory");
    __builtin_amdgcn_s_barrier();
}

// ws layout:
//   [0,      524288) : Npart f32[512][256]  (per-block numerator partials)
//   [524288, 526336) : spart f32[512]       (per-block denominator partials)
// pure overwrite -> no zero-init needed.

__global__ __launch_bounds__(256, 2) void attn_main(const float* __restrict__ x,
                                                    const float* __restrict__ W,
                                                    const float* __restrict__ bias,
                                                    const float* __restrict__ u,
                                                    float* __restrict__ Npart,
                                                    float* __restrict__ spart) {
    __shared__ char  xs[TM * DDIM * 2];      // 32 KB bf16 row-major (512 B/row), XOR-swizzled
    __shared__ float wpart[4][TM];           // per-wave 32-col row partials (1 KB)
    __shared__ float fpart[4][DDIM];         // pooling partials (4 KB)
    __shared__ float ssum_lds[4];

    const int bid  = blockIdx.x;
    const int b    = bid >> 3;                   // 8 blocks per batch
    const int t00  = (bid & 7) * (TILES * TM);
    const int tid  = threadIdx.x;
    const int wave = tid >> 6;
    const int lane = tid & 63;
    const int lm   = lane & 15;                  // col index within 16x16 C tile
    const int lk   = lane >> 4;                  // k-block / row-quad index

    // wave-cooperative row loads: wave w owns rows [w*16, w*16+16)
    const float* xw = x + ((size_t)(b * TLEN + t00) + wave * 16) * DDIM;

    // ---- prologue A: issue tile-0 x loads FIRST (1 KB contiguous per instr) ----
    f32x4 fa[16];
#pragma unroll
    for (int i = 0; i < 16; ++i)
        fa[i] = *(const f32x4*)(xw + i * DDIM + lane * 4);

    // ---- prologue B: W fragments direct from global (L2-hot, coalesced-16) ----
    // wave w owns A-columns [w*32, w*32+32); frag elem j <-> k = kt*32+lk*8+j
    bf16x8 wfreg[8][2];
#pragma unroll
    for (int kt = 0; kt < 8; ++kt)
#pragma unroll
        for (int ntl = 0; ntl < 2; ++ntl) {
            const float* wp = W + (size_t)(kt * 32 + lk * 8) * ADIM + wave * 32 + ntl * 16 + lm;
            bf16x8 w;
#pragma unroll
            for (int j = 0; j < 8; ++j) w[j] = (__bf16)wp[j * ADIM];
            wfreg[kt][ntl] = w;
        }

    float bias_r[2], u_r[2];
#pragma unroll
    for (int ntl = 0; ntl < 2; ++ntl) {
        bias_r[ntl] = bias[wave * 32 + ntl * 16 + lm];
        u_r[ntl]    = u[wave * 32 + ntl * 16 + lm];
    }

    f32x4 vacc4 = (f32x4){0.f, 0.f, 0.f, 0.f};  // cols lane*4..+4, this wave's rows
    float sreg = 0.f;                            // this wave's rows (lanes identical)

    for (int it = 0; it < TILES; ++it) {
        // ---- phase 1: cvt + stash current tile; KEEP bf16 copy in registers ----
        bf16x4 abf[16];
#pragma unroll
        for (int i = 0; i < 16; ++i) {
            const int row = wave * 16 + i;      // row & 7 == i & 7 (wave*16 % 8 == 0)
            bf16x4 a;
#pragma unroll
            for (int j = 0; j < 4; ++j) a[j] = (__bf16)fa[i][j];
            abf[i] = a;
            *(bf16x4*)(xs + ((row * 512 + lane * 8) ^ ((i & 7) << 4))) = a;
        }
        // ---- issue next tile's loads BEFORE the barrier (full tile in flight) ----
        if (it + 1 < TILES) {
            const float* xn = xw + (size_t)(it + 1) * TM * DDIM;
#pragma unroll
            for (int i = 0; i < 16; ++i)
                fa[i] = *(const f32x4*)(xn + i * DDIM + lane * 4);
        }
        bar_lds();   // bar#1: stash visible; prefetch stays in flight (no vmcnt drain)

        // ---- phase 2: GEMM (A from LDS, W from regs) + logits -> wpart ----
        f32x4 acc[4][2];
#pragma unroll
        for (int m = 0; m < 4; ++m)
#pragma unroll
            for (int ntl = 0; ntl < 2; ++ntl) acc[m][ntl] = (f32x4){0.f, 0.f, 0.f, 0.f};

#pragma unroll
        for (int kt = 0; kt < 8; ++kt) {
#pragma unroll
            for (int m = 0; m < 4; ++m) {
                const int r = m * 16 + lm;
                bf16x8 afrag = *(const bf16x8*)(xs + ((r * 512 + kt * 64 + lk * 16) ^ ((r & 7) << 4)));
                acc[m][0] = __builtin_amdgcn_mfma_f32_16x16x32_bf16(afrag, wfreg[kt][0], acc[m][0], 0, 0, 0);
                acc[m][1] = __builtin_amdgcn_mfma_f32_16x16x32_bf16(afrag, wfreg[kt][1], acc[m][1], 0, 0, 0);
            }
        }

#pragma unroll
        for (int m = 0; m < 4; ++m) {
#pragma unroll
            for (int reg = 0; reg < 4; ++reg) {
                float p = 0.f;
#pragma unroll
                for (int ntl = 0; ntl < 2; ++ntl) {
                    float lg = acc[m][ntl][reg] + bias_r[ntl];
                    float e  = __expf(2.0f * lg);
                    float th = 1.0f - 2.0f * __builtin_amdgcn_rcpf(e + 1.0f);  // tanh, inf-safe
                    p += th * u_r[ntl];
                }
                p = dpp_add<0xB1>(p);   // xor 1
                p = dpp_add<0x4E>(p);   // xor 2
                p = dpp_add<0x141>(p);  // row_half_mirror
                p = dpp_add<0x140>(p);  // row_mirror -> full 16-lane sum
                if (lm == 0) wpart[wave][m * 16 + lk * 4 + reg] = p;
            }
        }
        bar_lds();   // bar#2: wpart visible; also fences xs reads before next stash

        // ---- phase 3: weights for THIS wave's 16 rows (broadcast reads), pool
        //      from registers. No xs access -> no 3rd barrier needed. ----
        f32x4 zq[4];
#pragma unroll
        for (int q = 0; q < 4; ++q) {
            zq[q] = (f32x4){0.f, 0.f, 0.f, 0.f};
#pragma unroll
            for (int w = 0; w < 4; ++w)
                zq[q] += *(const f32x4*)&wpart[w][wave * 16 + q * 4];
        }
        float wv[16];
#pragma unroll
        for (int q = 0; q < 4; ++q)
#pragma unroll
            for (int i = 0; i < 4; ++i) wv[q * 4 + i] = __expf(zq[q][i]);
#pragma unroll
        for (int i = 0; i < 16; ++i) {
            sreg += wv[i];
#pragma unroll
            for (int j = 0; j < 4; ++j) vacc4[j] += (float)abf[i][j] * wv[i];
        }
        // next iteration's bar#1 fences wpart rewrite vs these reads
    }

    // ---- epilogue: denominator (all 64 lanes of a wave hold identical sreg) ----
    if (lane == 0) ssum_lds[wave] = sreg;

    // ---- epilogue: numerator (fold 4 waves via LDS; col d = lane*4+j) ----
    *(f32x4*)&fpart[wave][lane * 4] = vacc4;
    __syncthreads();
    if (tid == 0)
        spart[bid] = ssum_lds[0] + ssum_lds[1] + ssum_lds[2] + ssum_lds[3];
    Npart[(size_t)bid * DDIM + tid] =
          fpart[0][tid] + fpart[1][tid] + fpart[2][tid] + fpart[3][tid];
}

__global__ __launch_bounds__(256) void finalize_kernel(const float* __restrict__ Npart,
                                                       const float* __restrict__ spart,
                                                       float* __restrict__ out) {
    const int b = blockIdx.x;       // one block per batch
    const int d = threadIdx.x;
    float sb = 0.f;
#pragma unroll
    for (int i = 0; i < 8; ++i) sb += spart[b * 8 + i];
    float r = 0.f;
#pragma unroll
    for (int i = 0; i < 8; ++i) r += Npart[(size_t)(b * 8 + i) * DDIM + d];
    out[b * DDIM + d] = r / (sb + EPSC);
}

extern "C" void kernel_launch(void* const* d_in, const int* in_sizes, int n_in,
                              void* d_out, int out_size, void* d_ws, size_t ws_size,
                              hipStream_t stream) {
    const float* x    = (const float*)d_in[0];
    const float* W    = (const float*)d_in[1];
    const float* bias = (const float*)d_in[2];
    const float* u    = (const float*)d_in[3];
    float* out = (float*)d_out;

    char* ws = (char*)d_ws;
    float* Npart = (float*)ws;
    float* spart = (float*)(ws + 524288);

    attn_main<<<NBLK, 256, 0, stream>>>(x, W, bias, u, Npart, spart);
    finalize_kernel<<<BATCH, 256, 0, stream>>>(Npart, spart, out);
}

// Round 24
// 32.326 us; speedup vs baseline: 1.4405x; 1.4405x over previous
//
#include <hip/hip_runtime.h>

#define BATCH 64
#define TLEN  2048
#define DDIM  256
#define ADIM  128
#define TM    32          // t-rows per tile
#define TILES 8           // tiles per block
#define NBLK  (BATCH * TLEN / (TILES * TM))   // 512 blocks, 8 per batch: single co-resident round
#define EPSC  1e-7f

typedef __bf16 bf16x8 __attribute__((ext_vector_type(8)));
typedef __bf16 bf16x4 __attribute__((ext_vector_type(4)));
typedef float  f32x4  __attribute__((ext_vector_type(4)));

// DPP-based add of a lane-permuted copy (VALU pipe, not LDS)
template <int CTRL>
__device__ __forceinline__ float dpp_add(float v) {
    int vi = __builtin_bit_cast(int, v);
    int sw = __builtin_amdgcn_update_dpp(vi, vi, CTRL, 0xF, 0xF, false);
    return v + __builtin_bit_cast(float, sw);
}

// raw workgroup barrier: orders LDS only, leaves global loads (vmcnt) in flight
__device__ __forceinline__ void bar_lds() {
    asm volatile("s_waitcnt lgkmcnt(0)" ::: "memory");
    __builtin_amdgcn_s_barrier();
}

// ws layout:
//   [0,      524288) : Npart f32[512][256]  (per-block numerator partials)
//   [524288, 526336) : spart f32[512]       (per-block denominator partials)
// pure overwrite -> no zero-init needed.

__global__ __launch_bounds__(256, 2) void attn_main(const float* __restrict__ x,
                                                    const float* __restrict__ W,
                                                    const float* __restrict__ bias,
                                                    const float* __restrict__ u,
                                                    float* __restrict__ Npart,
                                                    float* __restrict__ spart) {
    __shared__ char  xs[TM * DDIM * 2];      // 16 KB bf16 row-major (512 B/row), XOR-swizzled
    __shared__ float wpart[4][TM];           // per-wave 32-col row partials (512 B)
    __shared__ float fpart[4][DDIM];         // pooling partials (4 KB)
    __shared__ float ssum_lds[4];

    const int bid  = blockIdx.x;
    const int b    = bid >> 3;                   // 8 blocks per batch
    const int t00  = (bid & 7) * (TILES * TM);
    const int tid  = threadIdx.x;
    const int wave = tid >> 6;
    const int lane = tid & 63;
    const int lm   = lane & 15;                  // col index within 16x16 C tile
    const int lk   = lane >> 4;                  // k-block / row-quad index

    // wave-cooperative row loads: wave w owns rows [w*8, w*8+8)
    const float* xw = x + ((size_t)(b * TLEN + t00) + wave * 8) * DDIM;

    // ---- prologue A: issue tile-0 x loads FIRST (1 KB contiguous per instr) ----
    f32x4 fa[8];
#pragma unroll
    for (int i = 0; i < 8; ++i)
        fa[i] = *(const f32x4*)(xw + i * DDIM + lane * 4);

    // ---- prologue B: W fragments direct from global (L2-hot, coalesced-16) ----
    // wave w owns A-columns [w*32, w*32+32); frag elem j <-> k = kt*32+lk*8+j
    bf16x8 wfreg[8][2];
#pragma unroll
    for (int kt = 0; kt < 8; ++kt)
#pragma unroll
        for (int ntl = 0; ntl < 2; ++ntl) {
            const float* wp = W + (size_t)(kt * 32 + lk * 8) * ADIM + wave * 32 + ntl * 16 + lm;
            bf16x8 w;
#pragma unroll
            for (int j = 0; j < 8; ++j) w[j] = (__bf16)wp[j * ADIM];
            wfreg[kt][ntl] = w;
        }

    float bias_r[2], u_r[2];
#pragma unroll
    for (int ntl = 0; ntl < 2; ++ntl) {
        bias_r[ntl] = bias[wave * 32 + ntl * 16 + lm];
        u_r[ntl]    = u[wave * 32 + ntl * 16 + lm];
    }

    f32x4 vacc4 = (f32x4){0.f, 0.f, 0.f, 0.f};  // cols lane*4..+4, this wave's rows
    float sreg = 0.f;                            // this wave's rows (lanes identical)

    for (int it = 0; it < TILES; ++it) {
        // ---- phase 1: cvt + stash current tile; KEEP bf16 copy in registers ----
        bf16x4 abf[8];
#pragma unroll
        for (int i = 0; i < 8; ++i) {
            const int row = wave * 8 + i;       // row & 7 == i
            bf16x4 a;
#pragma unroll
            for (int j = 0; j < 4; ++j) a[j] = (__bf16)fa[i][j];
            abf[i] = a;
            *(bf16x4*)(xs + ((row * 512 + lane * 8) ^ (i << 4))) = a;
        }
        // ---- issue next tile's loads BEFORE the barrier (full tile in flight) ----
        if (it + 1 < TILES) {
            const float* xn = xw + (size_t)(it + 1) * TM * DDIM;
#pragma unroll
            for (int i = 0; i < 8; ++i)
                fa[i] = *(const f32x4*)(xn + i * DDIM + lane * 4);
        }
        bar_lds();   // bar#1: stash visible; prefetch stays in flight (no vmcnt drain)

        // ---- phase 2: GEMM (A from LDS, W from regs) + logits -> wpart ----
        f32x4 acc[2][2];
#pragma unroll
        for (int m = 0; m < 2; ++m)
#pragma unroll
            for (int ntl = 0; ntl < 2; ++ntl) acc[m][ntl] = (f32x4){0.f, 0.f, 0.f, 0.f};

#pragma unroll
        for (int kt = 0; kt < 8; ++kt) {
#pragma unroll
            for (int m = 0; m < 2; ++m) {
                const int r = m * 16 + lm;
                bf16x8 afrag = *(const bf16x8*)(xs + ((r * 512 + kt * 64 + lk * 16) ^ ((r & 7) << 4)));
                acc[m][0] = __builtin_amdgcn_mfma_f32_16x16x32_bf16(afrag, wfreg[kt][0], acc[m][0], 0, 0, 0);
                acc[m][1] = __builtin_amdgcn_mfma_f32_16x16x32_bf16(afrag, wfreg[kt][1], acc[m][1], 0, 0, 0);
            }
        }

#pragma unroll
        for (int m = 0; m < 2; ++m) {
#pragma unroll
            for (int reg = 0; reg < 4; ++reg) {
                float p = 0.f;
#pragma unroll
                for (int ntl = 0; ntl < 2; ++ntl) {
                    float lg = acc[m][ntl][reg] + bias_r[ntl];
                    float e  = __expf(2.0f * lg);
                    float th = 1.0f - 2.0f * __builtin_amdgcn_rcpf(e + 1.0f);  // tanh, inf-safe
                    p += th * u_r[ntl];
                }
                p = dpp_add<0xB1>(p);   // xor 1
                p = dpp_add<0x4E>(p);   // xor 2
                p = dpp_add<0x141>(p);  // row_half_mirror
                p = dpp_add<0x140>(p);  // row_mirror -> full 16-lane sum
                if (lm == 0) wpart[wave][m * 16 + lk * 4 + reg] = p;
            }
        }
        bar_lds();   // bar#2: wpart visible; also fences xs reads before next stash

        // ---- phase 3: weights for THIS wave's 8 rows (broadcast reads), pool
        //      from registers. No xs access -> no 3rd barrier needed. ----
        f32x4 zlo = (f32x4){0.f, 0.f, 0.f, 0.f}, zhi = (f32x4){0.f, 0.f, 0.f, 0.f};
#pragma unroll
        for (int w = 0; w < 4; ++w) {
            zlo += *(const f32x4*)&wpart[w][wave * 8];
            zhi += *(const f32x4*)&wpart[w][wave * 8 + 4];
        }
        float wv[8];
#pragma unroll
        for (int i = 0; i < 4; ++i) { wv[i] = __expf(zlo[i]); wv[4 + i] = __expf(zhi[i]); }
#pragma unroll
        for (int i = 0; i < 8; ++i) {
            sreg += wv[i];
#pragma unroll
            for (int j = 0; j < 4; ++j) vacc4[j] += (float)abf[i][j] * wv[i];
        }
        // next iteration's bar#1 fences wpart rewrite vs these reads
    }

    // ---- epilogue: denominator (all 64 lanes of a wave hold identical sreg) ----
    if (lane == 0) ssum_lds[wave] = sreg;

    // ---- epilogue: numerator (fold 4 waves via LDS; col d = lane*4+j) ----
    *(f32x4*)&fpart[wave][lane * 4] = vacc4;
    __syncthreads();
    if (tid == 0)
        spart[bid] = ssum_lds[0] + ssum_lds[1] + ssum_lds[2] + ssum_lds[3];
    Npart[(size_t)bid * DDIM + tid] =
          fpart[0][tid] + fpart[1][tid] + fpart[2][tid] + fpart[3][tid];
}

__global__ __launch_bounds__(256) void finalize_kernel(const float* __restrict__ Npart,
                                                       const float* __restrict__ spart,
                                                       float* __restrict__ out) {
    const int b = blockIdx.x;       // one block per batch
    const int d = threadIdx.x;
    float sb = 0.f;
#pragma unroll
    for (int i = 0; i < 8; ++i) sb += spart[b * 8 + i];
    float r = 0.f;
#pragma unroll
    for (int i = 0; i < 8; ++i) r += Npart[(size_t)(b * 8 + i) * DDIM + d];
    out[b * DDIM + d] = r / (sb + EPSC);
}

extern "C" void kernel_launch(void* const* d_in, const int* in_sizes, int n_in,
                              void* d_out, int out_size, void* d_ws, size_t ws_size,
                              hipStream_t stream) {
    const float* x    = (const float*)d_in[0];
    const float* W    = (const float*)d_in[1];
    const float* bias = (const float*)d_in[2];
    const float* u    = (const float*)d_in[3];
    float* out = (float*)d_out;

    char* ws = (char*)d_ws;
    float* Npart = (float*)ws;
    float* spart = (float*)(ws + 524288);

    attn_main<<<NBLK, 256, 0, stream>>>(x, W, bias, u, Npart, spart);
    finalize_kernel<<<BATCH, 256, 0, stream>>>(Npart, spart, out);
}